// Round 5
// baseline (5985.080 us; speedup 1.0000x reference)
//
#include <hip/hip_runtime.h>
#include <hip/hip_bf16.h>

typedef __attribute__((ext_vector_type(8))) short   short8;
typedef __attribute__((ext_vector_type(4))) float   float4_;

// ---------------- workspace layout (bytes) ----------------
#define WPACK_OFF   0
#define WPACK_BYTES 786432                    // 1024 rows x 384 k x 2B, A-frag packed
#define HBUF_OFF    786432
#define HBUF_BYTES  4194304                   // 32 slots x 16grp x 16b x 256k x bf16
#define BIAS_OFF    (HBUF_OFF + HBUF_BYTES)   // 4980736
#define BIAS_BYTES  4096
#define FLAGS_OFF   (BIAS_OFF + BIAS_BYTES)   // 4984832
#define FLAGS_BYTES 2048                      // 16 groups x 32-int padded counters

#define SLOT_ULL 16384                        // 16grp*16bl*64 ulls per step-slot
#define SENT_ULL 0xFFFFFFFFFFFFFFFFull        // bf16 NaN x4 — unreachable for finite h

__device__ __forceinline__ unsigned short f2bf(float f) {
  unsigned int u = __float_as_uint(f);
  u += 0x7fffu + ((u >> 16) & 1u);            // round-to-nearest-even
  return (unsigned short)(u >> 16);
}

// Pack W = [W_hh | W_ih] into MFMA A-fragment order, bf16.
// idx = (((s*4+w)*4+mt)*12+kt)*64+lane ; each thread writes one 16B frag.
__global__ void pack_w(const float* __restrict__ w_ih,
                       const float* __restrict__ w_hh,
                       unsigned short* __restrict__ wpack) {
  int idx = blockIdx.x * blockDim.x + threadIdx.x;
  if (idx >= 49152) return;
  int lane = idx & 63;
  int r1 = idx >> 6;
  int kt = r1 % 12;
  int r2 = r1 / 12;
  int mt = r2 & 3;          // gate (i,f,g,o)
  int r3 = r2 >> 2;
  int w  = r3 & 3;          // wave in block
  int s  = r3 >> 2;         // gate-slice (which block of the group)
  int row = mt * 256 + s * 64 + w * 16 + (lane & 15);
  int q = lane >> 4;
  short8 o;
#pragma unroll
  for (int j = 0; j < 8; ++j) {
    int kk = kt * 32 + q * 8 + j;             // 0..383
    float v = (kt < 8) ? w_hh[row * 256 + kk]
                       : w_ih[row * 128 + (kk - 256)];
    o[j] = (short)f2bf(v);
  }
  *(short8*)(wpack + (size_t)idx * 8) = o;
}

// Fill hbuf: slot 0 = bf16(h0), slots 1..31 = sentinel. Also bias = b_ih+b_hh.
__global__ void init_hb(const float* __restrict__ h0,
                        const float* __restrict__ b_ih,
                        const float* __restrict__ b_hh,
                        unsigned long long* __restrict__ hbuf,
                        float* __restrict__ bias) {
  int idx = blockIdx.x * blockDim.x + threadIdx.x;
  if (idx < 16384) {                           // slot 0: seed h0 (4 halves per ull)
    unsigned long long v = 0;
#pragma unroll
    for (int e = 0; e < 4; ++e)
      v |= (unsigned long long)f2bf(h0[idx * 4 + e]) << (16 * e);
    hbuf[idx] = v;
  } else if (idx < 524288) {                   // slots 1..31: sentinel
    hbuf[idx] = SENT_ULL;
  } else if (idx < 525312) {
    int j = idx - 524288;
    bias[j] = b_ih[j] + b_hh[j];
  }
}

__device__ __forceinline__ float sigm_(float v) {
  return 1.f / (1.f + __expf(-v));
}
__device__ __forceinline__ float tanh_(float v) {
  return 1.f - 2.f / (__expf(2.f * v) + 1.f);  // robust at +-inf
}

__global__ __launch_bounds__(256, 1) void lstm_main(
    const float* __restrict__ x, const float* __restrict__ c0,
    const unsigned short* __restrict__ wpack, const float* __restrict__ bias,
    unsigned long long* hbuf, int* flags, float* __restrict__ out) {

  const int tid  = threadIdx.x;
  const int w    = tid >> 6;       // wave 0..3
  const int lane = tid & 63;
  const int q    = lane >> 4;
  const int bl   = lane & 15;

  // XCD-affinity swizzle: the 4 blocks of a group share blockIdx%8 (same XCD).
  int id  = blockIdx.x;
  int xcd = id & 7;
  int j3  = id >> 3;
  int s   = j3 & 3;                         // gate-slice 0..3
  int grp = (j3 >> 2) * 8 + xcd;            // batch group 0..15

  const int n0    = s * 64 + w * 16;        // wave's first h-element
  const int bglob = grp * 16 + bl;

  // ---- W fragments in VGPRs: 4 gates x 12 ktiles ----
  short8 wf[48];
  {
    const unsigned short* base =
        wpack + ((size_t)((s * 4 + w) * 48) * 64 + lane) * 8;
#pragma unroll
    for (int f = 0; f < 48; ++f)
      wf[f] = *(const short8*)(base + (size_t)f * 64 * 8);
  }
  // PIN: opaque asm touch makes each fragment a non-rematerializable register
  // value — the periodic acquire fence can no longer force an L2 reload.
#pragma unroll
  for (int f = 0; f < 48; ++f)
    asm volatile("" : "+v"(wf[f]));

  // bias (acc init), c state
  float4_ bia[4];
#pragma unroll
  for (int g = 0; g < 4; ++g)
    bia[g] = *(const float4_*)(bias + g * 256 + n0 + q * 4);
#pragma unroll
  for (int g = 0; g < 4; ++g)
    asm volatile("" : "+v"(bia[g]));
  float4_ c = *(const float4_*)(c0 + (size_t)bglob * 256 + n0 + q * 4);

  // x prefetch for t=0 (ktiles 8..11 of K)
  float4_ xr[8];
  {
    const float* xb = x + (size_t)bglob * 131072 + q * 8;
#pragma unroll
    for (int kx = 0; kx < 4; ++kx) {
      xr[kx * 2]     = *(const float4_*)(xb + kx * 32);
      xr[kx * 2 + 1] = *(const float4_*)(xb + kx * 32 + 4);
    }
  }

  // per-(grp,bl) ull base inside one step-slot; step slot adds (t&31)*SLOT_ULL
  const size_t hb_base = ((size_t)grp * 16 + bl) * 64;
  const size_t my_off  = hb_base + (n0 >> 2) + q;      // this wave's output chunk
  int* const cnt = &flags[grp * 32];

  float4_ hval;

#pragma unroll 1
  for (int t = 0; t < 1024; ++t) {
    // convert prefetched x -> bf16 frags (xr loaded a full step ago — covered)
    short8 xf[4];
#pragma unroll
    for (int kx = 0; kx < 4; ++kx) {
      short8 v;
#pragma unroll
      for (int e = 0; e < 4; ++e) {
        v[e]     = (short)f2bf(xr[kx * 2][e]);
        v[e + 4] = (short)f2bf(xr[kx * 2 + 1][e]);
      }
      xf[kx] = v;
    }

    // ---- poll h_t directly (data-embedded sync; the poll IS the load) ----
    // NOTE: no long-latency loads outstanding here — the poll's vmcnt(0)
    // covers only its own 16 LLC loads (vmcnt waits oldest-first; any HBM
    // prefetch issued before the poll would be dragged onto this wait).
    unsigned long long pl[16];
    {
      unsigned long long* hb = hbuf + (size_t)(t & 31) * SLOT_ULL + hb_base + q * 2;
      for (;;) {
#pragma unroll
        for (int ss = 0; ss < 4; ++ss) {
          pl[ss * 4 + 0] = __hip_atomic_load(hb + ss * 16 + 0, __ATOMIC_RELAXED, __HIP_MEMORY_SCOPE_AGENT);
          pl[ss * 4 + 1] = __hip_atomic_load(hb + ss * 16 + 1, __ATOMIC_RELAXED, __HIP_MEMORY_SCOPE_AGENT);
          pl[ss * 4 + 2] = __hip_atomic_load(hb + ss * 16 + 8, __ATOMIC_RELAXED, __HIP_MEMORY_SCOPE_AGENT);
          pl[ss * 4 + 3] = __hip_atomic_load(hb + ss * 16 + 9, __ATOMIC_RELAXED, __HIP_MEMORY_SCOPE_AGENT);
        }
        bool ok = true;
#pragma unroll
        for (int i = 0; i < 16; ++i)
          ok &= ((unsigned)(pl[i] & 0xFFFFull) != 0xFFFFu);
        if (__all(ok)) break;
        __builtin_amdgcn_s_sleep(1);
      }
    }

    // x prefetch for NEXT step — issued AFTER the poll so it never poisons
    // the poll's waitcnt; consumed at next iteration's top (~full step cover).
    {
      int tn = (t < 1023) ? (t + 1) : 1023;
      const float* xb = x + (size_t)bglob * 131072 + (size_t)tn * 128 + q * 8;
#pragma unroll
      for (int kx = 0; kx < 4; ++kx) {
        xr[kx * 2]     = *(const float4_*)(xb + kx * 32);
        xr[kx * 2 + 1] = *(const float4_*)(xb + kx * 32 + 4);
      }
    }

    float4_ acc[4];
#pragma unroll
    for (int g = 0; g < 4; ++g) acc[g] = bia[g];

    // x contribution (regs ready): ktiles 8..11
#pragma unroll
    for (int kx = 0; kx < 4; ++kx)
#pragma unroll
      for (int g = 0; g < 4; ++g)
        acc[g] = __builtin_amdgcn_mfma_f32_16x16x32_bf16(wf[g * 12 + 8 + kx], xf[kx], acc[g], 0, 0, 0);

    // h contribution: all 4 slices, fully static wf indices
#pragma unroll
    for (int ss = 0; ss < 4; ++ss) {
#pragma unroll
      for (int kt = 0; kt < 2; ++kt) {
        union { unsigned long long u[2]; short8 v; } uu;
        uu.u[0] = pl[ss * 4 + kt * 2 + 0];
        uu.u[1] = pl[ss * 4 + kt * 2 + 1];
#pragma unroll
        for (int g = 0; g < 4; ++g)
          acc[g] = __builtin_amdgcn_mfma_f32_16x16x32_bf16(wf[g * 12 + 2 * ss + kt], uu.v, acc[g], 0, 0, 0);
      }
    }

    // ---- gates / state update (fp32) ----
    unsigned short hp[4];
#pragma unroll
    for (int r = 0; r < 4; ++r) {
      float iv = sigm_(acc[0][r]);
      float fv = sigm_(acc[1][r]);
      float gv = tanh_(acc[2][r]);
      float ov = sigm_(acc[3][r]);
      float cv = fv * c[r] + iv * gv;
      c[r] = cv;
      float hv = ov * tanh_(cv);
      hval[r] = hv;
      hp[r] = f2bf(hv);
    }

    // write h_{t+1} chunk (single atomic 8B store -> slot (t+1)&31)
    {
      unsigned long long hu = (unsigned long long)hp[0]
                            | ((unsigned long long)hp[1] << 16)
                            | ((unsigned long long)hp[2] << 32)
                            | ((unsigned long long)hp[3] << 48);
      unsigned long long* dst = hbuf + (size_t)((t + 1) & 31) * SLOT_ULL + my_off;
      __hip_atomic_store(dst, hu, __ATOMIC_RELAXED, __HIP_MEMORY_SCOPE_AGENT);
    }

    // ---- every 8 steps: reset old slots + group barrier (amortized) ----
    if ((t & 7) == 7 && t != 1023) {
      const int k = t >> 3;                 // t == 8k+7
      // re-sentinel this wave's own chunks for steps m in [8k-15, 8k-8]
#pragma unroll
      for (int j = 0; j < 8; ++j) {
        int m = 8 * k - 15 + j;
        if (m >= 0) {
          unsigned long long* rp = hbuf + (size_t)(m & 31) * SLOT_ULL + my_off;
          __hip_atomic_store(rp, SENT_ULL, __ATOMIC_RELAXED, __HIP_MEMORY_SCOPE_AGENT);
        }
      }
      if (lane == 0)
        __hip_atomic_fetch_add(cnt, 1, __ATOMIC_RELEASE, __HIP_MEMORY_SCOPE_AGENT);
      const int target = 16 * (k + 1);
      for (;;) {
        int v = __hip_atomic_load(cnt, __ATOMIC_RELAXED, __HIP_MEMORY_SCOPE_AGENT);
        if (v >= target) break;
        __builtin_amdgcn_s_sleep(1);
      }
      __builtin_amdgcn_fence(__ATOMIC_ACQUIRE, "agent");
    }
  }

  // final h (fp32) -> d_out [1,B,H]
  *(float4_*)(out + (size_t)bglob * 256 + n0 + q * 4) = hval;
}

extern "C" void kernel_launch(void* const* d_in, const int* in_sizes, int n_in,
                              void* d_out, int out_size, void* d_ws, size_t ws_size,
                              hipStream_t stream) {
  (void)in_sizes; (void)n_in; (void)out_size; (void)ws_size;
  const float* x    = (const float*)d_in[0];
  const float* h0   = (const float*)d_in[1];
  const float* c0   = (const float*)d_in[2];
  const float* w_ih = (const float*)d_in[3];
  const float* w_hh = (const float*)d_in[4];
  const float* b_ih = (const float*)d_in[5];
  const float* b_hh = (const float*)d_in[6];

  char* ws = (char*)d_ws;
  unsigned short*     wpack = (unsigned short*)(ws + WPACK_OFF);
  unsigned long long* hbuf  = (unsigned long long*)(ws + HBUF_OFF);
  float*              bias  = (float*)(ws + BIAS_OFF);
  int*                flags = (int*)(ws + FLAGS_OFF);

  hipMemsetAsync(flags, 0, FLAGS_BYTES, stream);
  pack_w<<<192, 256, 0, stream>>>(w_ih, w_hh, wpack);
  init_hb<<<2053, 256, 0, stream>>>(h0, b_ih, b_hh, hbuf, bias);
  lstm_main<<<64, 256, 0, stream>>>(x, c0, wpack, bias, hbuf, flags,
                                    (float*)d_out);
}

// Round 6
// 5702.978 us; speedup vs baseline: 1.0495x; 1.0495x over previous
//
#include <hip/hip_runtime.h>
#include <hip/hip_bf16.h>

typedef __attribute__((ext_vector_type(8))) short   short8;
typedef __attribute__((ext_vector_type(4))) float   float4_;

// ---------------- workspace layout (bytes) ----------------
#define WPACK_OFF   0
#define WPACK_BYTES 786432                    // 1024 rows x 384 k x 2B, A-frag packed
#define HBUF_OFF    786432
#define HBUF_BYTES  4194304                   // 32 slots x 16grp x 16b x 256k x bf16
#define BIAS_OFF    (HBUF_OFF + HBUF_BYTES)   // 4980736
#define BIAS_BYTES  4096
#define FLAGS_OFF   (BIAS_OFF + BIAS_BYTES)   // 4984832
#define FLAGS_BYTES 2048                      // 16 groups x 32-int padded counters

#define SLOT_ULL 16384                        // 16grp*16bl*64 ulls per step-slot
#define SENT_ULL 0xFFFFFFFFFFFFFFFFull        // bf16 NaN x4 — unreachable for finite h

__device__ __forceinline__ unsigned short f2bf(float f) {
  unsigned int u = __float_as_uint(f);
  u += 0x7fffu + ((u >> 16) & 1u);            // round-to-nearest-even
  return (unsigned short)(u >> 16);
}

// Pack W = [W_hh | W_ih] into MFMA A-fragment order, bf16.
// idx = (((s*4+w)*4+mt)*12+kt)*64+lane ; each thread writes one 16B frag.
__global__ void pack_w(const float* __restrict__ w_ih,
                       const float* __restrict__ w_hh,
                       unsigned short* __restrict__ wpack) {
  int idx = blockIdx.x * blockDim.x + threadIdx.x;
  if (idx >= 49152) return;
  int lane = idx & 63;
  int r1 = idx >> 6;
  int kt = r1 % 12;
  int r2 = r1 / 12;
  int mt = r2 & 3;          // gate (i,f,g,o)
  int r3 = r2 >> 2;
  int w  = r3 & 3;          // wave in block
  int s  = r3 >> 2;         // gate-slice (which block of the group)
  int row = mt * 256 + s * 64 + w * 16 + (lane & 15);
  int q = lane >> 4;
  short8 o;
#pragma unroll
  for (int j = 0; j < 8; ++j) {
    int kk = kt * 32 + q * 8 + j;             // 0..383
    float v = (kt < 8) ? w_hh[row * 256 + kk]
                       : w_ih[row * 128 + (kk - 256)];
    o[j] = (short)f2bf(v);
  }
  *(short8*)(wpack + (size_t)idx * 8) = o;
}

// Fill hbuf: slot 0 = bf16(h0), slots 1..31 = sentinel. Also bias = b_ih+b_hh.
__global__ void init_hb(const float* __restrict__ h0,
                        const float* __restrict__ b_ih,
                        const float* __restrict__ b_hh,
                        unsigned long long* __restrict__ hbuf,
                        float* __restrict__ bias) {
  int idx = blockIdx.x * blockDim.x + threadIdx.x;
  if (idx < 16384) {                           // slot 0: seed h0 (4 halves per ull)
    unsigned long long v = 0;
#pragma unroll
    for (int e = 0; e < 4; ++e)
      v |= (unsigned long long)f2bf(h0[idx * 4 + e]) << (16 * e);
    hbuf[idx] = v;
  } else if (idx < 524288) {                   // slots 1..31: sentinel
    hbuf[idx] = SENT_ULL;
  } else if (idx < 525312) {
    int j = idx - 524288;
    bias[j] = b_ih[j] + b_hh[j];
  }
}

__device__ __forceinline__ float sigm_(float v) {
  return 1.f / (1.f + __expf(-v));
}
__device__ __forceinline__ float tanh_(float v) {
  return 1.f - 2.f / (__expf(2.f * v) + 1.f);  // robust at +-inf
}

__global__ __launch_bounds__(256, 1) void lstm_main(
    const float* __restrict__ x, const float* __restrict__ c0,
    const unsigned short* __restrict__ wpack, const float* __restrict__ bias,
    unsigned long long* hbuf, int* flags, float* __restrict__ out) {

  const int tid  = threadIdx.x;
  const int w    = tid >> 6;       // wave 0..3
  const int lane = tid & 63;
  const int q    = lane >> 4;
  const int bl   = lane & 15;

  // XCD-affinity swizzle: the 4 blocks of a group share blockIdx%8 (same XCD).
  int id  = blockIdx.x;
  int xcd = id & 7;
  int j3  = id >> 3;
  int s   = j3 & 3;                         // gate-slice 0..3
  int grp = (j3 >> 2) * 8 + xcd;            // batch group 0..15

  const int n0    = s * 64 + w * 16;        // wave's first h-element
  const int bglob = grp * 16 + bl;

  // ---- W fragments pinned in AGPRs: 4 gates x 12 ktiles ----
  // gfx950 MFMA reads A from VGPR or AGPR (unified file). The AGPR file is
  // otherwise idle; "+a" pins make the 192 regs of W unspillable values the
  // allocator must keep resident — no scratch, no L2 re-stream per step.
  short8 wf[48];
  {
    const unsigned short* base =
        wpack + ((size_t)((s * 4 + w) * 48) * 64 + lane) * 8;
#pragma unroll
    for (int f = 0; f < 48; ++f)
      wf[f] = *(const short8*)(base + (size_t)f * 64 * 8);
  }
#pragma unroll
  for (int f = 0; f < 48; ++f)
    asm volatile("" : "+a"(wf[f]));

  // bias (acc init) pinned in AGPRs too; c state stays VGPR
  float4_ bia[4];
#pragma unroll
  for (int g = 0; g < 4; ++g)
    bia[g] = *(const float4_*)(bias + g * 256 + n0 + q * 4);
#pragma unroll
  for (int g = 0; g < 4; ++g)
    asm volatile("" : "+a"(bia[g]));
  float4_ c = *(const float4_*)(c0 + (size_t)bglob * 256 + n0 + q * 4);

  // x prefetch for t=0 (ktiles 8..11 of K)
  float4_ xr[8];
  {
    const float* xb = x + (size_t)bglob * 131072 + q * 8;
#pragma unroll
    for (int kx = 0; kx < 4; ++kx) {
      xr[kx * 2]     = *(const float4_*)(xb + kx * 32);
      xr[kx * 2 + 1] = *(const float4_*)(xb + kx * 32 + 4);
    }
  }

  // per-(grp,bl) ull base inside one step-slot; step slot adds (t&31)*SLOT_ULL
  const size_t hb_base = ((size_t)grp * 16 + bl) * 64;
  const size_t my_off  = hb_base + (n0 >> 2) + q;      // this wave's output chunk
  int* const cnt = &flags[grp * 32];

  float4_ hval;

#pragma unroll 1
  for (int t = 0; t < 1024; ++t) {
    // convert prefetched x -> bf16 frags (xr loaded a full step ago — covered)
    short8 xf[4];
#pragma unroll
    for (int kx = 0; kx < 4; ++kx) {
      short8 v;
#pragma unroll
      for (int e = 0; e < 4; ++e) {
        v[e]     = (short)f2bf(xr[kx * 2][e]);
        v[e + 4] = (short)f2bf(xr[kx * 2 + 1][e]);
      }
      xf[kx] = v;
    }

    // ---- poll h_t directly (data-embedded sync; the poll IS the load) ----
    // No long-latency vmem may be outstanding here: vmcnt waits oldest-first,
    // so an HBM prefetch issued before the poll would be dragged onto every
    // poll retry's wait.
    unsigned long long pl[16];
    {
      unsigned long long* hb = hbuf + (size_t)(t & 31) * SLOT_ULL + hb_base + q * 2;
      for (;;) {
#pragma unroll
        for (int ss = 0; ss < 4; ++ss) {
          pl[ss * 4 + 0] = __hip_atomic_load(hb + ss * 16 + 0, __ATOMIC_RELAXED, __HIP_MEMORY_SCOPE_AGENT);
          pl[ss * 4 + 1] = __hip_atomic_load(hb + ss * 16 + 1, __ATOMIC_RELAXED, __HIP_MEMORY_SCOPE_AGENT);
          pl[ss * 4 + 2] = __hip_atomic_load(hb + ss * 16 + 8, __ATOMIC_RELAXED, __HIP_MEMORY_SCOPE_AGENT);
          pl[ss * 4 + 3] = __hip_atomic_load(hb + ss * 16 + 9, __ATOMIC_RELAXED, __HIP_MEMORY_SCOPE_AGENT);
        }
        bool ok = true;
#pragma unroll
        for (int i = 0; i < 16; ++i)
          ok &= ((unsigned)(pl[i] & 0xFFFFull) != 0xFFFFu);
        if (__all(ok)) break;
        __builtin_amdgcn_s_sleep(1);
      }
    }
    // compiler barrier: forbid hoisting the x prefetch above the poll
    asm volatile("" ::: "memory");

    // x prefetch for NEXT step — issued AFTER the poll so it never poisons
    // the poll's waitcnt; consumed at next iteration's top (~full step cover).
    {
      int tn = (t < 1023) ? (t + 1) : 1023;
      const float* xb = x + (size_t)bglob * 131072 + (size_t)tn * 128 + q * 8;
#pragma unroll
      for (int kx = 0; kx < 4; ++kx) {
        xr[kx * 2]     = *(const float4_*)(xb + kx * 32);
        xr[kx * 2 + 1] = *(const float4_*)(xb + kx * 32 + 4);
      }
    }

    float4_ acc[4];
#pragma unroll
    for (int g = 0; g < 4; ++g) acc[g] = bia[g];

    // x contribution (regs ready): ktiles 8..11
#pragma unroll
    for (int kx = 0; kx < 4; ++kx)
#pragma unroll
      for (int g = 0; g < 4; ++g)
        acc[g] = __builtin_amdgcn_mfma_f32_16x16x32_bf16(wf[g * 12 + 8 + kx], xf[kx], acc[g], 0, 0, 0);

    // h contribution: all 4 slices, fully static wf indices
#pragma unroll
    for (int ss = 0; ss < 4; ++ss) {
#pragma unroll
      for (int kt = 0; kt < 2; ++kt) {
        union { unsigned long long u[2]; short8 v; } uu;
        uu.u[0] = pl[ss * 4 + kt * 2 + 0];
        uu.u[1] = pl[ss * 4 + kt * 2 + 1];
#pragma unroll
        for (int g = 0; g < 4; ++g)
          acc[g] = __builtin_amdgcn_mfma_f32_16x16x32_bf16(wf[g * 12 + 2 * ss + kt], uu.v, acc[g], 0, 0, 0);
      }
    }

    // ---- gates / state update (fp32) ----
    unsigned short hp[4];
#pragma unroll
    for (int r = 0; r < 4; ++r) {
      float iv = sigm_(acc[0][r]);
      float fv = sigm_(acc[1][r]);
      float gv = tanh_(acc[2][r]);
      float ov = sigm_(acc[3][r]);
      float cv = fv * c[r] + iv * gv;
      c[r] = cv;
      float hv = ov * tanh_(cv);
      hval[r] = hv;
      hp[r] = f2bf(hv);
    }

    // write h_{t+1} chunk (single atomic 8B store -> slot (t+1)&31)
    {
      unsigned long long hu = (unsigned long long)hp[0]
                            | ((unsigned long long)hp[1] << 16)
                            | ((unsigned long long)hp[2] << 32)
                            | ((unsigned long long)hp[3] << 48);
      unsigned long long* dst = hbuf + (size_t)((t + 1) & 31) * SLOT_ULL + my_off;
      __hip_atomic_store(dst, hu, __ATOMIC_RELAXED, __HIP_MEMORY_SCOPE_AGENT);
    }

    // ---- every 8 steps: reset old slots + group barrier (amortized) ----
    if ((t & 7) == 7 && t != 1023) {
      const int k = t >> 3;                 // t == 8k+7
      // re-sentinel this wave's own chunks for steps m in [8k-15, 8k-8]
#pragma unroll
      for (int j = 0; j < 8; ++j) {
        int m = 8 * k - 15 + j;
        if (m >= 0) {
          unsigned long long* rp = hbuf + (size_t)(m & 31) * SLOT_ULL + my_off;
          __hip_atomic_store(rp, SENT_ULL, __ATOMIC_RELAXED, __HIP_MEMORY_SCOPE_AGENT);
        }
      }
      if (lane == 0)
        __hip_atomic_fetch_add(cnt, 1, __ATOMIC_RELEASE, __HIP_MEMORY_SCOPE_AGENT);
      const int target = 16 * (k + 1);
      for (;;) {
        int v = __hip_atomic_load(cnt, __ATOMIC_RELAXED, __HIP_MEMORY_SCOPE_AGENT);
        if (v >= target) break;
        __builtin_amdgcn_s_sleep(1);
      }
      __builtin_amdgcn_fence(__ATOMIC_ACQUIRE, "agent");
    }
  }

  // final h (fp32) -> d_out [1,B,H]
  *(float4_*)(out + (size_t)bglob * 256 + n0 + q * 4) = hval;
}

extern "C" void kernel_launch(void* const* d_in, const int* in_sizes, int n_in,
                              void* d_out, int out_size, void* d_ws, size_t ws_size,
                              hipStream_t stream) {
  (void)in_sizes; (void)n_in; (void)out_size; (void)ws_size;
  const float* x    = (const float*)d_in[0];
  const float* h0   = (const float*)d_in[1];
  const float* c0   = (const float*)d_in[2];
  const float* w_ih = (const float*)d_in[3];
  const float* w_hh = (const float*)d_in[4];
  const float* b_ih = (const float*)d_in[5];
  const float* b_hh = (const float*)d_in[6];

  char* ws = (char*)d_ws;
  unsigned short*     wpack = (unsigned short*)(ws + WPACK_OFF);
  unsigned long long* hbuf  = (unsigned long long*)(ws + HBUF_OFF);
  float*              bias  = (float*)(ws + BIAS_OFF);
  int*                flags = (int*)(ws + FLAGS_OFF);

  hipMemsetAsync(flags, 0, FLAGS_BYTES, stream);
  pack_w<<<192, 256, 0, stream>>>(w_ih, w_hh, wpack);
  init_hb<<<2053, 256, 0, stream>>>(h0, b_ih, b_hh, hbuf, bias);
  lstm_main<<<64, 256, 0, stream>>>(x, c0, wpack, bias, hbuf, flags,
                                    (float*)d_out);
}

// Round 7
// 5218.177 us; speedup vs baseline: 1.1470x; 1.0929x over previous
//
#include <hip/hip_runtime.h>
#include <hip/hip_bf16.h>

typedef __attribute__((ext_vector_type(8))) short   short8;
typedef __attribute__((ext_vector_type(4))) float   float4_;
typedef __attribute__((ext_vector_type(2))) float   float2_;

// ---------------- workspace layout (bytes) ----------------
#define WPACK_OFF   0
#define WPACK_BYTES 786432                    // 1024 rows x 384 k x 2B, A-frag packed
#define HBUF_OFF    786432
#define HBUF_BYTES  4194304                   // 32 slots x 16grp x 16b x 256k x bf16
#define BIAS_OFF    (HBUF_OFF + HBUF_BYTES)   // 4980736
#define BIAS_BYTES  4096
#define FLAGS_OFF   (BIAS_OFF + BIAS_BYTES)   // 4984832
#define FLAGS_BYTES 2048                      // 16 groups x 32-int padded counters

#define SLOT_ULL 16384                        // ulls per step-slot (16grp*16b*64)
#define SLOT_U32 32768                        // uints per step-slot
#define SENT_U32 0xFFFFFFFFu                  // bf16 NaN x2 — unreachable for finite h

__device__ __forceinline__ unsigned short f2bf(float f) {
  unsigned int u = __float_as_uint(f);
  u += 0x7fffu + ((u >> 16) & 1u);            // round-to-nearest-even
  return (unsigned short)(u >> 16);
}

// Pack W = [W_hh | W_ih] into MFMA A-fragment order, bf16.
// idx = ((((s*4+w)*2+m)*12)+kt)*64+lane ; block s owns rows gate*256 + [s*32,s*32+32).
__global__ void pack_w(const float* __restrict__ w_ih,
                       const float* __restrict__ w_hh,
                       unsigned short* __restrict__ wpack) {
  int idx = blockIdx.x * blockDim.x + threadIdx.x;
  if (idx >= 49152) return;
  int lane = idx & 63;
  int r1 = idx >> 6;
  int kt = r1 % 12;
  int r2 = r1 / 12;
  int m  = r2 & 1;          // mtile within slice (16 rows)
  int r3 = r2 >> 1;
  int w  = r3 & 3;          // gate (i,f,g,o) == wave
  int s  = r3 >> 2;         // slice 0..7
  int row = w * 256 + s * 32 + m * 16 + (lane & 15);
  int q = lane >> 4;
  short8 o;
#pragma unroll
  for (int j = 0; j < 8; ++j) {
    int kk = kt * 32 + q * 8 + j;             // 0..383
    float v = (kt < 8) ? w_hh[row * 256 + kk]
                       : w_ih[row * 128 + (kk - 256)];
    o[j] = (short)f2bf(v);
  }
  *(short8*)(wpack + (size_t)idx * 8) = o;
}

// Fill hbuf: slot 0 = bf16(h0), slots 1..31 = sentinel. Also bias = b_ih+b_hh.
__global__ void init_hb(const float* __restrict__ h0,
                        const float* __restrict__ b_ih,
                        const float* __restrict__ b_hh,
                        unsigned long long* __restrict__ hbuf,
                        float* __restrict__ bias) {
  int idx = blockIdx.x * blockDim.x + threadIdx.x;
  if (idx < 16384) {                           // slot 0: seed h0 (4 halves per ull)
    unsigned long long v = 0;
#pragma unroll
    for (int e = 0; e < 4; ++e)
      v |= (unsigned long long)f2bf(h0[idx * 4 + e]) << (16 * e);
    hbuf[idx] = v;
  } else if (idx < 524288) {                   // slots 1..31: sentinel
    hbuf[idx] = 0xFFFFFFFFFFFFFFFFull;
  } else if (idx < 525312) {
    int j = idx - 524288;
    bias[j] = b_ih[j] + b_hh[j];
  }
}

__device__ __forceinline__ float sigm_(float v) {
  return 1.f / (1.f + __expf(-v));
}
__device__ __forceinline__ float tanh_(float v) {
  return 1.f - 2.f / (__expf(2.f * v) + 1.f);  // robust at +-inf
}

__global__ __launch_bounds__(256, 1) void lstm_main(
    const float* __restrict__ x, const float* __restrict__ c0,
    const unsigned short* __restrict__ wpack, const float* __restrict__ bias,
    unsigned long long* hbuf, int* flags, float* __restrict__ out) {

  const int tid  = threadIdx.x;
  const int w    = tid >> 6;       // wave == gate 0..3
  const int lane = tid & 63;
  const int q    = lane >> 4;
  const int bl   = lane & 15;

  const int id  = blockIdx.x;
  const int grp = id >> 3;                  // batch group 0..15
  const int s   = id & 7;                   // n-slice 0..7 (32 elems)

  // combiner-role constants: thread (np,b) owns h/c for n = s*32+2np+{0,1}, batch b
  const int np = tid >> 4;                  // 0..15
  const int b  = tid & 15;
  const int nglob   = s * 32 + 2 * np;
  const int bglob_c = grp * 16 + b;

  // ---- W fragments in VGPRs: 2 mtiles x 12 ktiles = 24 frags (96 regs) ----
  short8 wf[24];
  {
    const unsigned short* base =
        wpack + ((size_t)((s * 4 + w) * 24) * 64 + lane) * 8;
#pragma unroll
    for (int f = 0; f < 24; ++f)
      wf[f] = *(const short8*)(base + (size_t)f * 64 * 8);
  }
#pragma unroll
  for (int f = 0; f < 24; ++f)
    asm volatile("" : "+v"(wf[f]));          // 96 pinned + ~130 live < 256: safe

  // bias for gate w (acc init)
  float4_ bia[2];
#pragma unroll
  for (int m = 0; m < 2; ++m)
    bia[m] = *(const float4_*)(bias + w * 256 + s * 32 + m * 16 + q * 4);

  // c state (combiner role)
  float cst[2];
  cst[0] = c0[(size_t)bglob_c * 256 + nglob];
  cst[1] = c0[(size_t)bglob_c * 256 + nglob + 1];

  // x prefetch for t=0 (ktiles 8..11); B-frag batch = grp*16+bl
  float4_ xr[8];
  {
    const float* xb = x + (size_t)(grp * 16 + bl) * 131072 + q * 8;
#pragma unroll
    for (int kx = 0; kx < 4; ++kx) {
      xr[kx * 2]     = *(const float4_*)(xb + kx * 32);
      xr[kx * 2 + 1] = *(const float4_*)(xb + kx * 32 + 4);
    }
  }

  // hbuf addressing
  const size_t hb_base = ((size_t)grp * 16 + bl) * 64;            // consumer (ull)
  const size_t my_u32  = ((size_t)grp * 16 + b) * 128 + s * 16 + np;  // producer (uint)
  unsigned int* const hbuf32 = (unsigned int*)hbuf;
  int* const cnt = &flags[grp * 32];

  // gate-exchange LDS: [gate][n_local 32][b 16+pad]
  __shared__ float glds[4][32][17];

  float hout[2];

#pragma unroll 1
  for (int t = 0; t < 1024; ++t) {
    // convert prefetched x -> bf16 frags (xr issued ~a full step ago)
    short8 xf[4];
#pragma unroll
    for (int kx = 0; kx < 4; ++kx) {
      short8 v;
#pragma unroll
      for (int e = 0; e < 4; ++e) {
        v[e]     = (short)f2bf(xr[kx * 2][e]);
        v[e + 4] = (short)f2bf(xr[kx * 2 + 1][e]);
      }
      xf[kx] = v;
    }

    // ---- poll h_t (data-embedded sync; the poll IS the load) ----
    // Each 8B ull holds two independently-produced 4B chunks: check both halves.
    unsigned long long pl[16];
    {
      unsigned long long* hb =
          hbuf + (size_t)(t & 31) * SLOT_ULL + hb_base + q * 2;
      for (;;) {
#pragma unroll
        for (int kt = 0; kt < 8; ++kt) {
          pl[kt * 2]     = __hip_atomic_load(hb + kt * 8,     __ATOMIC_RELAXED, __HIP_MEMORY_SCOPE_AGENT);
          pl[kt * 2 + 1] = __hip_atomic_load(hb + kt * 8 + 1, __ATOMIC_RELAXED, __HIP_MEMORY_SCOPE_AGENT);
        }
        bool ok = true;
#pragma unroll
        for (int i = 0; i < 16; ++i) {
          ok &= ((unsigned)(pl[i] & 0xFFFFull) != 0xFFFFu);
          ok &= ((unsigned)((pl[i] >> 32) & 0xFFFFull) != 0xFFFFu);
        }
        if (__all(ok)) break;
        __builtin_amdgcn_s_sleep(1);
      }
    }
    asm volatile("" ::: "memory");   // nothing hoists above the poll

    float4_ acc[2];
#pragma unroll
    for (int m = 0; m < 2; ++m) acc[m] = bia[m];

    // x contribution: ktiles 8..11
#pragma unroll
    for (int kx = 0; kx < 4; ++kx)
#pragma unroll
      for (int m = 0; m < 2; ++m)
        acc[m] = __builtin_amdgcn_mfma_f32_16x16x32_bf16(wf[m * 12 + 8 + kx], xf[kx], acc[m], 0, 0, 0);

    // h contribution: ktiles 0..7
#pragma unroll
    for (int kt = 0; kt < 8; ++kt) {
      union { unsigned long long u[2]; short8 v; } uu;
      uu.u[0] = pl[kt * 2];
      uu.u[1] = pl[kt * 2 + 1];
#pragma unroll
      for (int m = 0; m < 2; ++m)
        acc[m] = __builtin_amdgcn_mfma_f32_16x16x32_bf16(wf[m * 12 + kt], uu.v, acc[m], 0, 0, 0);
    }

    // publish gate-w pre-activations to LDS (C-layout: col=bl, row=q*4+r)
#pragma unroll
    for (int m = 0; m < 2; ++m)
#pragma unroll
      for (int r = 0; r < 4; ++r)
        glds[w][m * 16 + q * 4 + r][bl] = acc[m][r];

    __syncthreads();

    // x prefetch for NEXT step — after the barrier so no waitcnt drains it early
    {
      int tn = (t < 1023) ? (t + 1) : 1023;
      const float* xb = x + (size_t)(grp * 16 + bl) * 131072 + (size_t)tn * 128 + q * 8;
#pragma unroll
      for (int kx = 0; kx < 4; ++kx) {
        xr[kx * 2]     = *(const float4_*)(xb + kx * 32);
        xr[kx * 2 + 1] = *(const float4_*)(xb + kx * 32 + 4);
      }
    }

    // ---- combine all 4 gates for this thread's 2 (n,b) elements ----
    unsigned short hp[2];
#pragma unroll
    for (int dn = 0; dn < 2; ++dn) {
      int nl = 2 * np + dn;
      float iv = sigm_(glds[0][nl][b]);
      float fv = sigm_(glds[1][nl][b]);
      float gv = tanh_(glds[2][nl][b]);
      float ov = sigm_(glds[3][nl][b]);
      float cv = fv * cst[dn] + iv * gv;
      cst[dn] = cv;
      float hv = ov * tanh_(cv);
      hout[dn] = hv;
      hp[dn] = f2bf(hv);
    }

    // write h_{t+1} chunk: ONE 4B atomic store per thread
    {
      unsigned int hu = (unsigned int)hp[0] | ((unsigned int)hp[1] << 16);
      unsigned int* dst = hbuf32 + (size_t)((t + 1) & 31) * SLOT_U32 + my_u32;
      __hip_atomic_store(dst, hu, __ATOMIC_RELAXED, __HIP_MEMORY_SCOPE_AGENT);
    }

    // ---- every 8 steps: reset old slots + group barrier (amortized) ----
    if ((t & 7) == 7 && t != 1023) {
      const int k = t >> 3;                 // t == 8k+7
#pragma unroll
      for (int j = 0; j < 8; ++j) {
        int m = 8 * k - 15 + j;             // steps consumed >= 2 windows ago
        if (m >= 0) {
          unsigned int* rp = hbuf32 + (size_t)(m & 31) * SLOT_U32 + my_u32;
          __hip_atomic_store(rp, SENT_U32, __ATOMIC_RELAXED, __HIP_MEMORY_SCOPE_AGENT);
        }
      }
      __syncthreads();                      // drain whole block's stores (vmcnt0)
      if (tid == 0)
        __hip_atomic_fetch_add(cnt, 1, __ATOMIC_RELEASE, __HIP_MEMORY_SCOPE_AGENT);
      const int target = 8 * (k + 1);       // 8 blocks per group
      for (;;) {
        int v = __hip_atomic_load(cnt, __ATOMIC_RELAXED, __HIP_MEMORY_SCOPE_AGENT);
        if (v >= target) break;
        __builtin_amdgcn_s_sleep(1);
      }
      __builtin_amdgcn_fence(__ATOMIC_ACQUIRE, "agent");
    }
  }

  // final h (fp32) -> d_out [1,B,H]
  {
    float2_ o2; o2[0] = hout[0]; o2[1] = hout[1];
    *(float2_*)(out + (size_t)bglob_c * 256 + nglob) = o2;
  }
}

extern "C" void kernel_launch(void* const* d_in, const int* in_sizes, int n_in,
                              void* d_out, int out_size, void* d_ws, size_t ws_size,
                              hipStream_t stream) {
  (void)in_sizes; (void)n_in; (void)out_size; (void)ws_size;
  const float* x    = (const float*)d_in[0];
  const float* h0   = (const float*)d_in[1];
  const float* c0   = (const float*)d_in[2];
  const float* w_ih = (const float*)d_in[3];
  const float* w_hh = (const float*)d_in[4];
  const float* b_ih = (const float*)d_in[5];
  const float* b_hh = (const float*)d_in[6];

  char* ws = (char*)d_ws;
  unsigned short*     wpack = (unsigned short*)(ws + WPACK_OFF);
  unsigned long long* hbuf  = (unsigned long long*)(ws + HBUF_OFF);
  float*              bias  = (float*)(ws + BIAS_OFF);
  int*                flags = (int*)(ws + FLAGS_OFF);

  hipMemsetAsync(flags, 0, FLAGS_BYTES, stream);
  pack_w<<<192, 256, 0, stream>>>(w_ih, w_hh, wpack);
  init_hb<<<2053, 256, 0, stream>>>(h0, b_ih, b_hh, hbuf, bias);
  lstm_main<<<128, 256, 0, stream>>>(x, c0, wpack, bias, hbuf, flags,
                                     (float*)d_out);
}